// Round 3
// baseline (415.388 us; speedup 1.0000x reference)
//
#include <hip/hip_runtime.h>

// Correlation (FlowNet-style), kernel=1, stride=1, md=pad=4.
// B=8, C=128, H=W=192 -> out [8, 81, 192, 192] fp32.
//
// Round-3 design: no LDS; register-blocked 8 px/thread + prefetch.
//  - 576 tiles (8 b x 3 xt x 24 yt), tile = 8 rows x 64 cols.
//  - 3 dy-groups per tile -> grid 1728 blocks of 192 threads (3 waves).
//    wave w of group g owns dy = g*3 + w; the 3 waves share x2 rows via L1,
//    the 3 g-blocks of a tile are XCD-adjacent via the swizzle (L2).
//  - per thread: 8 consecutive x pixels; per channel load 2 x1 float4 +
//    4 x2 float4 (16-float window xb-4..xb+11 covers all 9 dx) -> 72 FMA.
//  - register double-buffer: issue c+1 loads, compute c, rotate.
//  - acc[9 dx][8 px] = 72 VGPRs.

#define NT 192

__global__ __launch_bounds__(NT)
void corr_kernel(const float* __restrict__ x1g, const float* __restrict__ x2g,
                 float* __restrict__ outg) {
  constexpr int Cc = 128, Hh = 192, Ww = 192;
  constexpr int HW = Hh * Ww;  // 36864

  // XCD-chunked swizzle: 1728 = 8 XCDs x 216; g fastest, then yt.
  const int bid = blockIdx.x;
  const int wid = (bid & 7) * 216 + (bid >> 3);
  const int tile = wid / 3;          // 0..575
  const int g    = wid - 3 * tile;   // 0..2
  const int yt = tile % 24;
  const int t2 = tile / 24;
  const int xt = t2 % 3;
  const int b  = t2 / 3;

  const int w    = (int)threadIdx.x >> 6;  // 0..2
  const int lane = (int)threadIdx.x & 63;
  const int tx   = lane & 7;               // 8 threads x 8 px = 64 cols
  const int ty   = lane >> 3;              // 8 rows
  const int dy   = g * 3 + w;              // 0..8

  const int y  = yt * 8 + ty;
  const int xb = xt * 64 + tx * 8;
  const int row = y + dy - 4;
  const bool rowok = (row >= 0) && (row < Hh);
  const int rowc = rowok ? row : 0;

  // 16-float x2 window: cols xb-4 .. xb+11 (16B-aligned float4 slots).
  const bool ok0 = rowok && (xb >= 4);     // cols xb-4..xb-1
  const bool ok1 = rowok;                  // cols xb  ..xb+7 (always in-range)
  const bool ok3 = rowok && (xb <= 180);   // cols xb+8..xb+11

  const float* p1 = x1g + ((size_t)(b * Cc) * Hh + y) * Ww + xb;
  const float* p2 = x2g + ((size_t)(b * Cc) * Hh + rowc) * Ww + (xb - 4);

  float acc[9][8];
#pragma unroll
  for (int d = 0; d < 9; ++d)
#pragma unroll
    for (int q = 0; q < 8; ++q) acc[d][q] = 0.f;

  const float4 z4 = make_float4(0.f, 0.f, 0.f, 0.f);
  float4 a0, a1, c0, c1, c2, c3;

  // prologue: load channel 0
  a0 = *(const float4*)(p1);
  a1 = *(const float4*)(p1 + 4);
  c0 = z4; c1 = z4; c2 = z4; c3 = z4;
  if (ok0) c0 = *(const float4*)(p2);
  if (ok1) { c1 = *(const float4*)(p2 + 4); c2 = *(const float4*)(p2 + 8); }
  if (ok3) c3 = *(const float4*)(p2 + 12);
  p1 += HW; p2 += HW;

#pragma unroll 2
  for (int c = 0; c < Cc - 1; ++c) {
    // issue next channel's loads (latency hidden under the 72 FMAs below)
    float4 na0 = *(const float4*)(p1);
    float4 na1 = *(const float4*)(p1 + 4);
    float4 n0 = z4, n1 = z4, n2 = z4, n3 = z4;
    if (ok0) n0 = *(const float4*)(p2);
    if (ok1) { n1 = *(const float4*)(p2 + 4); n2 = *(const float4*)(p2 + 8); }
    if (ok3) n3 = *(const float4*)(p2 + 12);
    p1 += HW; p2 += HW;

    const float av[8] = {a0.x, a0.y, a0.z, a0.w, a1.x, a1.y, a1.z, a1.w};
    const float rv[16] = {c0.x, c0.y, c0.z, c0.w, c1.x, c1.y, c1.z, c1.w,
                          c2.x, c2.y, c2.z, c2.w, c3.x, c3.y, c3.z, c3.w};
#pragma unroll
    for (int dx = 0; dx < 9; ++dx)
#pragma unroll
      for (int q = 0; q < 8; ++q) acc[dx][q] += av[q] * rv[dx + q];

    a0 = na0; a1 = na1; c0 = n0; c1 = n1; c2 = n2; c3 = n3;
  }

  {  // final channel
    const float av[8] = {a0.x, a0.y, a0.z, a0.w, a1.x, a1.y, a1.z, a1.w};
    const float rv[16] = {c0.x, c0.y, c0.z, c0.w, c1.x, c1.y, c1.z, c1.w,
                          c2.x, c2.y, c2.z, c2.w, c3.x, c3.y, c3.z, c3.w};
#pragma unroll
    for (int dx = 0; dx < 9; ++dx)
#pragma unroll
      for (int q = 0; q < 8; ++q) acc[dx][q] += av[q] * rv[dx + q];
  }

  // epilogue: out[b][dy*9+dx][y][xb..xb+7]
  const float invc = 1.0f / 128.0f;
#pragma unroll
  for (int dx = 0; dx < 9; ++dx) {
    float4 o0, o1;
    o0.x = acc[dx][0] * invc; o0.y = acc[dx][1] * invc;
    o0.z = acc[dx][2] * invc; o0.w = acc[dx][3] * invc;
    o1.x = acc[dx][4] * invc; o1.y = acc[dx][5] * invc;
    o1.z = acc[dx][6] * invc; o1.w = acc[dx][7] * invc;
    const size_t oidx =
        (((size_t)b * 81 + (dy * 9 + dx)) * Hh + y) * Ww + xb;
    *(float4*)&outg[oidx] = o0;
    *(float4*)&outg[oidx + 4] = o1;
  }
}

extern "C" void kernel_launch(void* const* d_in, const int* in_sizes, int n_in,
                              void* d_out, int out_size, void* d_ws, size_t ws_size,
                              hipStream_t stream) {
  const float* x1 = (const float*)d_in[0];
  const float* x2 = (const float*)d_in[1];
  float* out = (float*)d_out;
  // grid: 576 tiles x 3 dy-groups = 1728 blocks (divisible by 8 XCDs)
  corr_kernel<<<dim3(1728), dim3(NT), 0, stream>>>(x1, x2, out);
}